// Round 3
// baseline (10.093 us; speedup 1.0000x reference)
//
#include <hip/hip_runtime.h>

#define N_CTRL 64
#define NSEG 67.0f    // N_KNOTS - 1 = 67 spans over [0,1]
#define NPAD 72       // 3 zeros + 64 ctrl + 3 zeros, rounded up

typedef float float4v __attribute__((ext_vector_type(4)));  // clang-native, OK for nontemporal builtins

// Cubic B-spline on uniform knots, closed-form basis. Control points staged
// in LDS with 3-element zero padding on each side so the 4-tap gather needs
// no index clipping (reference's truncated basis table == clip == pad-zero).
__global__ __launch_bounds__(256) void spline_eval_kernel(
    const float* __restrict__ x,
    const float* __restrict__ ctrl,
    float* __restrict__ out,
    int n4, int n)
{
    __shared__ float cp[NPAD];
    if (threadIdx.x < NPAD) {
        int src = (int)threadIdx.x - 3;
        cp[threadIdx.x] = (src >= 0 && src < N_CTRL) ? ctrl[src] : 0.0f;
    }
    __syncthreads();

    const float4v* __restrict__ x4 = (const float4v*)x;
    float4v* __restrict__ o4 = (float4v*)out;

    int idx = blockIdx.x * blockDim.x + threadIdx.x;
    int stride = gridDim.x * blockDim.x;

    const float c6 = 1.0f / 6.0f;
    const float twothird = 2.0f / 3.0f;

    for (int i = idx; i < n4; i += stride) {
        float4v xv = x4[i];
        float4v yv;
        #pragma unroll
        for (int k = 0; k < 4; ++k) {
            float u = xv[k] * NSEG;
            int j = (int)u;
            j = j > 66 ? 66 : j;     // guard float edge at x ~= 1.0
            j = j < 0 ? 0 : j;
            float s = u - (float)j;           // in [0,1)
            float om = 1.0f - s;
            float s2 = s * s;
            float b0 = om * om * om * c6;                 // weight for ctrl[j-3]
            float b3 = s2 * s * c6;                       // weight for ctrl[j]
            float b1 = fmaf(-0.5f * s2, 2.0f - s, twothird);
            float b2 = 1.0f - b0 - b1 - b3;               // partition of unity
            // padded gather: cp[j+m] == ctrl[j-3+m], zeros outside [0,64)
            float acc = b3 * cp[j + 3];
            acc = fmaf(b2, cp[j + 2], acc);
            acc = fmaf(b1, cp[j + 1], acc);
            acc = fmaf(b0, cp[j], acc);
            yv[k] = acc;
        }
        __builtin_nontemporal_store(yv, &o4[i]);
    }

    // Scalar tail (n % 4 != 0) — not taken for N=1e6 but kept for safety.
    int t = n4 * 4 + idx;
    if (t < n) {
        float u = x[t] * NSEG;
        int j = (int)u;
        j = j > 66 ? 66 : j;
        j = j < 0 ? 0 : j;
        float s = u - (float)j;
        float om = 1.0f - s;
        float s2 = s * s;
        float b0 = om * om * om * c6;
        float b3 = s2 * s * c6;
        float b1 = fmaf(-0.5f * s2, 2.0f - s, twothird);
        float b2 = 1.0f - b0 - b1 - b3;
        float acc = b3 * cp[j + 3];
        acc = fmaf(b2, cp[j + 2], acc);
        acc = fmaf(b1, cp[j + 1], acc);
        acc = fmaf(b0, cp[j], acc);
        out[t] = acc;
    }
}

extern "C" void kernel_launch(void* const* d_in, const int* in_sizes, int n_in,
                              void* d_out, int out_size, void* d_ws, size_t ws_size,
                              hipStream_t stream) {
    const float* x    = (const float*)d_in[0];
    // d_in[1] = knots (uniform linspace(0,1,68)) — closed-form, not needed.
    const float* ctrl = (const float*)d_in[2];
    float* out = (float*)d_out;

    int n  = in_sizes[0];       // 1,000,000
    int n4 = n / 4;             // float4 chunks (exactly 250,000)

    int block = 256;
    int grid = (n4 + block - 1) / block;  // ~977 blocks
    if (grid < 1) grid = 1;

    spline_eval_kernel<<<grid, block, 0, stream>>>(x, ctrl, out, n4, n);
}